// Round 11
// baseline (65.730 us; speedup 1.0000x reference)
//
#include <hip/hip_runtime.h>
#include <math.h>

#define NF    64      // filters
#define KT    402     // taps: arange(-201, 201)
#define KP    416     // padded taps = 13 * 32
#define NSTEP 13      // K-steps of 32
#define LIN   16000
#define LOUT  15599   // LIN - KT + 1
#define NB    16
#define NT    256     // output positions per block (16 subtiles x 16)
#define SPAN  672     // NT + KP data span per block
#define NCHUNK 84     // SPAN / 8 staging chunks
#define SROW  680     // LDS copy-row stride (elems): 1360 B; 20 dwords mod 32
                      // -> 8 copy-rows hit distinct banks (conflict-free)
#define TT    256     // 4 waves per block

typedef __attribute__((ext_vector_type(8))) short short8;   // 8 bf16 (4 VGPR)
typedef __attribute__((ext_vector_type(4))) float f32x4;    // MFMA acc

// fp32 planes [plane][k][f] for the complex fallback path.
__device__ float g_filt[2 * KT * NF];
// B operand pre-packed in MFMA fragment order: [plane][group][s][lane][j].
// Value = bf16 split of coef(filter = 16*group + (lane&15),
//                            tap    = 8*(lane>>4) + 32*s + j).
// Each [plane][group][s] slice is 1 KB contiguous -> bulk global_load_lds.
__device__ __align__(16) short g_cbf[2][4][NSTEP][64][8];

__device__ __forceinline__ short f2bf(float v) {
    unsigned u = __float_as_uint(v);
    unsigned r = (u + 0x7fffu + ((u >> 16) & 1u)) >> 16;   // RNE
    return (short)r;
}
__device__ __forceinline__ float bf2f(short s) {
    return __uint_as_float(((unsigned)(unsigned short)s) << 16);
}
// Async global->LDS 16B copy: per-lane global src, wave-uniform LDS base
// (HW appends lane*16 to the destination).
__device__ __forceinline__ void gll16(const void* g, void* l) {
    __builtin_amdgcn_global_load_lds(
        (const __attribute__((address_space(1))) void*)g,
        (__attribute__((address_space(3))) void*)l, 16, 0, 0);
}

__global__ void gabor_build_filters(const float* __restrict__ cf,
                                    const float* __restrict__ bw) {
    int idx = blockIdx.x * blockDim.x + threadIdx.x;    // f*KP + k
    if (idx >= NF * KP) return;
    int f = idx / KP;
    int k = idx - f * KP;
    float cre = 0.0f;
    if (k < KT) {
        float t = (float)(k - 201);
        float b = bw[f];
        float env = expf(-(t * t) / (2.0f * b * b)) / (sqrtf(2.0f * (float)M_PI) * b);
        float s, c;
        sincosf(cf[f] * t, &s, &c);
        cre = env * c;
        g_filt[k * NF + f]           = cre;      // re plane (fallback)
        g_filt[KT * NF + k * NF + f] = env * s;  // im plane (fallback)
    }
    short hi = f2bf(cre);
    short lo = f2bf(cre - bf2f(hi));
    // scatter into fragment order: lane = (f&15) | q<<4, with k = 32s + 8q + j
    int g = f >> 4;
    int s = k >> 5;
    int q = (k >> 3) & 3;
    int j = k & 7;
    int l = (f & 15) | (q << 4);
    g_cbf[0][g][s][l][j] = hi;
    g_cbf[1][g][s][l][j] = lo;
}

// MFMA implicit GEMM, real part only. m97-style 2-barrier K-loop:
// BOTH operands read from LDS (compiler emits fine-grained lgkmcnt for
// ds_read->MFMA -- the only pipelining form hipcc preserves; R6/R7/R10
// post-mortems: register prefetch of global B loads is always discarded).
// Per block: 256 positions x all 64 filters x batch b; 4 waves, wave w =
// position-subtiles 4w..4w+3 x 4 groups (acc[4][4] = 64, R8's shape).
// Per step: stage next B-chunk (8 KB, 2x global_load_lds/thread; each wave
// copies one contiguous 1 KB fragment slice per round) into the idle half
// of a double buffer; 8 B + 8 A ds_read_b128; 48 MFMA; one barrier.
// A (Hankel of x) via 8 shifted bf16 copies (copy c holds elem i at i-c ->
// every fragment one aligned ds_read_b128; same-addr lanes broadcast).
// 3-term bf16 split (Ah*Bh + Al*Bh + Ah*Bl) emulates fp32.
__global__ __launch_bounds__(TT, 3) void gabor_conv_mfma(const float* __restrict__ x,
                                                         float* __restrict__ out,
                                                         long out_elems) {
    __shared__ __align__(16) short sxh[8][SROW];
    __shared__ __align__(16) short sxl[8][SROW];
    __shared__ __align__(16) short blds[2][8][64][8];   // [buf][phi][lane][j], 16 KB

    const int tile = blockIdx.x;
    const int b    = blockIdx.y;
    const int n0   = tile * NT;
    const int tid  = threadIdx.x;
    const int wid  = tid >> 6;      // 0..3
    const int lane = tid & 63;

    // Issue B-chunk for s=0 early (phi = wid and 4+wid; contiguous 1KB each).
    gll16(&g_cbf[0][wid][0][lane][0], &blds[0][wid][0][0]);
    gll16(&g_cbf[1][wid][0][lane][0], &blds[0][4 + wid][0][0]);

    // ---- Vectorized A staging: thread j < 84 owns x elements [8j, 8j+16),
    // builds all 8 shifted windows in registers, writes 16 ds_write_b128.
    if (tid < NCHUNK) {
        const int j  = tid;
        const int e0 = 8 * j;
        const float* __restrict__ src = x + (size_t)b * LIN + n0 + e0;

        float xv[16];
        if (n0 + e0 + 16 <= LIN) {
#pragma unroll
            for (int q = 0; q < 4; ++q) {
                float4 v = *reinterpret_cast<const float4*>(src + 4 * q);
                xv[4 * q + 0] = v.x; xv[4 * q + 1] = v.y;
                xv[4 * q + 2] = v.z; xv[4 * q + 3] = v.w;
            }
        } else {
#pragma unroll
            for (int i = 0; i < 16; ++i) {
                int gi = n0 + e0 + i;
                xv[i] = (gi < LIN) ? src[i] : 0.0f;
            }
        }

        unsigned hd[8], ld[8];   // packed bf16 pairs (low16 = even elem)
#pragma unroll
        for (int i = 0; i < 8; ++i) {
            unsigned h0 = (unsigned short)f2bf(xv[2 * i]);
            unsigned h1 = (unsigned short)f2bf(xv[2 * i + 1]);
            hd[i] = h0 | (h1 << 16);
            unsigned l0 = (unsigned short)f2bf(xv[2 * i]     - bf2f((short)h0));
            unsigned l1 = (unsigned short)f2bf(xv[2 * i + 1] - bf2f((short)h1));
            ld[i] = l0 | (l1 << 16);
        }

#pragma unroll
        for (int c = 0; c < 8; ++c) {
            unsigned wh[4], wl[4];
            if ((c & 1) == 0) {
#pragma unroll
                for (int i = 0; i < 4; ++i) {
                    wh[i] = hd[c / 2 + i];
                    wl[i] = ld[c / 2 + i];
                }
            } else {
#pragma unroll
                for (int i = 0; i < 4; ++i) {
                    int k2 = (c - 1) / 2 + i;
                    wh[i] = (hd[k2] >> 16) | (hd[k2 + 1] << 16);   // v_alignbit
                    wl[i] = (ld[k2] >> 16) | (ld[k2 + 1] << 16);
                }
            }
            uint4 vh = {wh[0], wh[1], wh[2], wh[3]};
            uint4 vl = {wl[0], wl[1], wl[2], wl[3]};
            *reinterpret_cast<uint4*>(&sxh[c][e0]) = vh;
            *reinterpret_cast<uint4*>(&sxl[c][e0]) = vl;
        }
    }
    __syncthreads();    // drains A ds_writes + B0 global_load_lds

    // ---- MFMA phase
    const int c8    = lane & 7;
    const int abase = 8 * ((lane >> 3) & 1) + 8 * (lane >> 4);
    const int subbase = wid * 4;    // this wave's first position-subtile
    const short* ah_p = &sxh[c8][abase + 16 * subbase];
    const short* al_p = &sxl[c8][abase + 16 * subbase];

    f32x4 acc[4][4];                // [n][group], all-static indexing
#pragma unroll
    for (int n = 0; n < 4; ++n)
#pragma unroll
        for (int g = 0; g < 4; ++g) {
            f32x4 z = {0.0f, 0.0f, 0.0f, 0.0f};
            acc[n][g] = z;
        }

#pragma unroll
    for (int s = 0; s < NSTEP; ++s) {
        const int cur = s & 1;
        // Stage step s+1's B-chunk into the idle buffer half.
        if (s + 1 < NSTEP) {
            gll16(&g_cbf[0][wid][s + 1][lane][0], &blds[cur ^ 1][wid][0][0]);
            gll16(&g_cbf[1][wid][s + 1][lane][0], &blds[cur ^ 1][4 + wid][0][0]);
        }
        short8 bh[4], bl[4];
#pragma unroll
        for (int g = 0; g < 4; ++g) {
            bh[g] = *(const short8*)(&blds[cur][g][lane][0]);
            bl[g] = *(const short8*)(&blds[cur][4 + g][lane][0]);
        }
#pragma unroll
        for (int n = 0; n < 4; ++n) {
            short8 ah = *(const short8*)(ah_p + 16 * n + 32 * s);
            short8 al = *(const short8*)(al_p + 16 * n + 32 * s);
#pragma unroll
            for (int g = 0; g < 4; ++g) {
                acc[n][g] = __builtin_amdgcn_mfma_f32_16x16x32_bf16(ah, bh[g], acc[n][g], 0, 0, 0);
                acc[n][g] = __builtin_amdgcn_mfma_f32_16x16x32_bf16(al, bh[g], acc[n][g], 0, 0, 0);
                acc[n][g] = __builtin_amdgcn_mfma_f32_16x16x32_bf16(ah, bl[g], acc[n][g], 0, 0, 0);
            }
        }
        __syncthreads();    // waves done with buf[cur]; buf[cur^1] staged
    }

    // D: col = lane&15 = filter-in-group, rows 4*(lane>>4)+0..3 = consecutive
    // positions. Scalar dword stores (measured clean 66 MB WRITE_SIZE in R7).
    const int r0 = 4 * (lane >> 4);
#pragma unroll
    for (int n = 0; n < 4; ++n) {
        const int np = n0 + 16 * (subbase + n) + r0;
#pragma unroll
        for (int g = 0; g < 4; ++g) {
            const int f = 16 * g + (lane & 15);
            const size_t o = (size_t)(b * NF + f) * LOUT + np;
#pragma unroll
            for (int r = 0; r < 4; ++r)
                if (np + r < LOUT && (long)(o + r) < out_elems)
                    out[o + r] = acc[n][g][r];
        }
    }
}

// Complex fallback (folded fp32) in case d_out is interleaved complex.
__global__ __launch_bounds__(256) void gabor_conv_cplx(const float* __restrict__ x,
                                                       float* __restrict__ out,
                                                       long out_elems) {
    __shared__ float sx[256 + KT];
    const int tile = blockIdx.x, g = blockIdx.y, b = blockIdx.z;
    const int t0 = tile * 256, tid = threadIdx.x;
    const float* __restrict__ xb = x + (size_t)b * LIN;
    for (int i = tid; i < 256 + KT - 1; i += 256) {
        int idx = t0 + i;
        sx[i] = (idx < LIN) ? xb[idx] : 0.0f;
    }
    __syncthreads();
    const float* fre = g_filt + g * 16;
    const float* fim = g_filt + KT * NF + g * 16;
    float accre[16], accim[16];
    {
        float x0 = sx[tid], xm = sx[tid + 201];
        const float* c0 = fre;
        const float* cm = fre + 201 * NF;
#pragma unroll
        for (int j = 0; j < 16; ++j) accre[j] = __builtin_fmaf(xm, cm[j], x0 * c0[j]);
#pragma unroll
        for (int j = 0; j < 16; ++j) accim[j] = x0 * fim[j];
    }
#pragma unroll 2
    for (int p = 1; p <= 200; ++p) {
        float x1 = sx[tid + p], x2 = sx[tid + 402 - p];
        float xs = x1 + x2, xd = x1 - x2;
        const float* cr = fre + p * NF;
        const float* ci = fim + p * NF;
#pragma unroll
        for (int j = 0; j < 16; ++j) accre[j] = __builtin_fmaf(xs, cr[j], accre[j]);
#pragma unroll
        for (int j = 0; j < 16; ++j) accim[j] = __builtin_fmaf(xd, ci[j], accim[j]);
    }
    const int t = t0 + tid;
    if (t < LOUT) {
#pragma unroll
        for (int j = 0; j < 16; ++j) {
            size_t o = ((size_t)(b * NF + g * 16 + j) * LOUT + t) * 2;
            if ((long)(o + 1) < out_elems) {
                float2 v; v.x = accre[j]; v.y = accim[j];
                *reinterpret_cast<float2*>(out + o) = v;
            }
        }
    }
}

extern "C" void kernel_launch(void* const* d_in, const int* in_sizes, int n_in,
                              void* d_out, int out_size, void* d_ws, size_t ws_size,
                              hipStream_t stream) {
    const float* x  = (const float*)d_in[0];
    const float* cf = (const float*)d_in[1];
    const float* bw = (const float*)d_in[2];
    float* out = (float*)d_out;
    (void)d_ws; (void)ws_size;

    {
        int n = NF * KP;
        gabor_build_filters<<<(n + 255) / 256, 256, 0, stream>>>(cf, bw);
    }

    const long n_complex = (long)NB * NF * LOUT;
    const bool cplx = ((long)out_size >= 2 * n_complex);

    if (cplx) {
        dim3 grid((LOUT + 255) / 256, NF / 16, NB);
        gabor_conv_cplx<<<grid, 256, 0, stream>>>(x, out, (long)out_size);
    } else {
        dim3 grid((LOUT + NT - 1) / NT, NB);   // (61, 16)
        gabor_conv_mfma<<<grid, TT, 0, stream>>>(x, out, (long)out_size);
    }
}

// Round 12
// 44.202 us; speedup vs baseline: 1.4870x; 1.4870x over previous
//
#include <hip/hip_runtime.h>
#include <math.h>

#define NF    64      // filters
#define KT    402     // taps: arange(-201, 201)
#define KP    416     // padded taps = 13 * 32
#define NSTEP 13      // K-steps of 32
#define LIN   16000
#define LOUT  15599   // LIN - KT + 1
#define NB    16
#define NT    128     // output positions per block (8 subtiles x 16)
#define SPAN  544     // NT + KP data span per block
#define NCHUNK 68     // SPAN / 8 staging chunks
#define SROW  552     // LDS copy-row stride (elems)
#define CPAD  132     // C-tile row stride (dwords): 132 mod 32 = 4 -> lane
                      // stride 4 banks, conflict-free b128 scatter by rows
#define TT    128     // 2 waves per block

typedef __attribute__((ext_vector_type(8))) short short8;   // 8 bf16 (4 VGPR)
typedef __attribute__((ext_vector_type(4))) float f32x4;    // MFMA acc
typedef __attribute__((ext_vector_type(4), aligned(4))) float f32x4u; // 4B-aligned store

// fp32 planes [plane][k][f] for the complex fallback path.
__device__ float g_filt[2 * KT * NF];
// B operand pre-packed in MFMA fragment order: [plane][group][s][lane][j].
// Value = bf16 split of coef(filter = 16*group + (lane&15),
//                            tap    = 8*(lane>>4) + 32*s + j).
__device__ __align__(16) short g_cbf[2][4][NSTEP][64][8];

__device__ __forceinline__ short f2bf(float v) {
    unsigned u = __float_as_uint(v);
    unsigned r = (u + 0x7fffu + ((u >> 16) & 1u)) >> 16;   // RNE
    return (short)r;
}
__device__ __forceinline__ float bf2f(short s) {
    return __uint_as_float(((unsigned)(unsigned short)s) << 16);
}

__global__ void gabor_build_filters(const float* __restrict__ cf,
                                    const float* __restrict__ bw) {
    int idx = blockIdx.x * blockDim.x + threadIdx.x;    // f*KP + k
    if (idx >= NF * KP) return;
    int f = idx / KP;
    int k = idx - f * KP;
    float cre = 0.0f;
    if (k < KT) {
        float t = (float)(k - 201);
        float b = bw[f];
        float env = expf(-(t * t) / (2.0f * b * b)) / (sqrtf(2.0f * (float)M_PI) * b);
        float s, c;
        sincosf(cf[f] * t, &s, &c);
        cre = env * c;
        g_filt[k * NF + f]           = cre;      // re plane (fallback)
        g_filt[KT * NF + k * NF + f] = env * s;  // im plane (fallback)
    }
    short hi = f2bf(cre);
    short lo = f2bf(cre - bf2f(hi));
    // scatter into fragment order: lane = (f&15) | q<<4, with k = 32s + 8q + j
    int g = f >> 4;
    int s = k >> 5;
    int q = (k >> 3) & 3;
    int j = k & 7;
    int l = (f & 15) | (q << 4);
    g_cbf[0][g][s][l][j] = hi;
    g_cbf[1][g][s][l][j] = lo;
}

// MFMA implicit GEMM, real part only. R8's compute structure verbatim (best
// measured K-loop: fully unrolled, B fragments loaded from global at use,
// barrier-free; 44.2 us) with ONE change: the epilogue.
// R12 epilogue: scatter acc into a padded f32 C-tile in LDS (reusing the
// A-stage buffers via union), then stream it out with lanes covering
// consecutive positions of a row -- contiguous 512 B per instruction,
// ~8 line-transactions vs ~16-32 scattered 4 B ones (R8 post-mortem: the
// 64-scalar-store row-scattered epilogue amplified L2 requests ~16x and
// capped effective write BW at ~1.5 TB/s).
// A (Hankel of x) from LDS via 8 shifted bf16 copies (copy c holds elem i at
// index i-c -> every fragment one aligned ds_read_b128).
// 3-term bf16 split (Ah*Bh + Al*Bh + Ah*Bl) emulates fp32.
__global__ __launch_bounds__(TT, 3) void gabor_conv_mfma(const float* __restrict__ x,
                                                         float* __restrict__ out,
                                                         long out_elems) {
    __shared__ __align__(16) union {
        struct { short h[8][SROW]; short l[8][SROW]; } a;  // 17,664 B
        float c[NF][CPAD];                                 // 33,792 B
    } sm;

    const int tile = blockIdx.x;
    const int b    = blockIdx.y;
    const int n0   = tile * NT;
    const int tid  = threadIdx.x;
    const int wid  = tid >> 6;      // 0..1
    const int lane = tid & 63;

    // ---- Vectorized staging: thread j < 68 owns x elements [8j, 8j+16),
    // builds all 8 shifted windows in registers, writes 16 ds_write_b128.
    if (tid < NCHUNK) {
        const int j  = tid;
        const int e0 = 8 * j;
        const float* __restrict__ src = x + (size_t)b * LIN + n0 + e0;

        float xv[16];
        if (n0 + e0 + 16 <= LIN) {
#pragma unroll
            for (int q = 0; q < 4; ++q) {
                float4 v = *reinterpret_cast<const float4*>(src + 4 * q);
                xv[4 * q + 0] = v.x; xv[4 * q + 1] = v.y;
                xv[4 * q + 2] = v.z; xv[4 * q + 3] = v.w;
            }
        } else {
#pragma unroll
            for (int i = 0; i < 16; ++i) {
                int gi = n0 + e0 + i;
                xv[i] = (gi < LIN) ? src[i] : 0.0f;
            }
        }

        unsigned hd[8], ld[8];   // packed bf16 pairs (low16 = even elem)
#pragma unroll
        for (int i = 0; i < 8; ++i) {
            unsigned h0 = (unsigned short)f2bf(xv[2 * i]);
            unsigned h1 = (unsigned short)f2bf(xv[2 * i + 1]);
            hd[i] = h0 | (h1 << 16);
            unsigned l0 = (unsigned short)f2bf(xv[2 * i]     - bf2f((short)h0));
            unsigned l1 = (unsigned short)f2bf(xv[2 * i + 1] - bf2f((short)h1));
            ld[i] = l0 | (l1 << 16);
        }

#pragma unroll
        for (int c = 0; c < 8; ++c) {
            unsigned wh[4], wl[4];
            if ((c & 1) == 0) {
#pragma unroll
                for (int i = 0; i < 4; ++i) {
                    wh[i] = hd[c / 2 + i];
                    wl[i] = ld[c / 2 + i];
                }
            } else {
#pragma unroll
                for (int i = 0; i < 4; ++i) {
                    int k2 = (c - 1) / 2 + i;
                    wh[i] = (hd[k2] >> 16) | (hd[k2 + 1] << 16);   // v_alignbit
                    wl[i] = (ld[k2] >> 16) | (ld[k2 + 1] << 16);
                }
            }
            uint4 vh = {wh[0], wh[1], wh[2], wh[3]};
            uint4 vl = {wl[0], wl[1], wl[2], wl[3]};
            *reinterpret_cast<uint4*>(&sm.a.h[c][e0]) = vh;
            *reinterpret_cast<uint4*>(&sm.a.l[c][e0]) = vl;
        }
    }
    __syncthreads();

    // ---- MFMA phase (R8 verbatim)
    const int c8    = lane & 7;
    const int abase = 8 * ((lane >> 3) & 1) + 8 * (lane >> 4);
    const short* ah_base = &sm.a.h[c8][abase];
    const short* al_base = &sm.a.l[c8][abase];
    const int subbase = wid * 4;    // this wave's first position-subtile

    f32x4 acc[4][4];                // [n][group], all-static indexing
#pragma unroll
    for (int n = 0; n < 4; ++n)
#pragma unroll
        for (int g = 0; g < 4; ++g) {
            f32x4 z = {0.0f, 0.0f, 0.0f, 0.0f};
            acc[n][g] = z;
        }

#pragma unroll
    for (int s = 0; s < NSTEP; ++s) {
        short8 bh[4], bl[4];
#pragma unroll
        for (int g = 0; g < 4; ++g) {
            bh[g] = *(const short8*)(&g_cbf[0][g][s][lane][0]);
            bl[g] = *(const short8*)(&g_cbf[1][g][s][lane][0]);
        }
#pragma unroll
        for (int n = 0; n < 4; ++n) {
            const int m = subbase + n + 2 * s;
            short8 ah = *(const short8*)(ah_base + 16 * m);
            short8 al = *(const short8*)(al_base + 16 * m);
#pragma unroll
            for (int g = 0; g < 4; ++g) {
                acc[n][g] = __builtin_amdgcn_mfma_f32_16x16x32_bf16(ah, bh[g], acc[n][g], 0, 0, 0);
                acc[n][g] = __builtin_amdgcn_mfma_f32_16x16x32_bf16(al, bh[g], acc[n][g], 0, 0, 0);
                acc[n][g] = __builtin_amdgcn_mfma_f32_16x16x32_bf16(ah, bl[g], acc[n][g], 0, 0, 0);
            }
        }
    }

    // ---- Epilogue: LDS transpose -> coalesced stores.
    __syncthreads();    // all waves done reading sm.a before clobbering sm.c

    // Scatter: D col = lane&15 = filter-in-group, rows 4*(lane>>4)+r are 4
    // consecutive positions -> one aligned b128 LDS write per (n,g).
#pragma unroll
    for (int n = 0; n < 4; ++n) {
        const int colbase = 16 * (subbase + n) + 4 * (lane >> 4);
#pragma unroll
        for (int g = 0; g < 4; ++g) {
            const int row = 16 * g + (lane & 15);
            *reinterpret_cast<f32x4*>(&sm.c[row][colbase]) = acc[n][g];
        }
    }
    __syncthreads();

    // Stream out: per instruction, 2 rows x 32 lanes x dwordx4 = 512 B
    // contiguous per row. Wave w handles rows 32w..32w+31.
    const int colr  = 4 * (lane & 31);
    const int rhalf = lane >> 5;    // 0..1
#pragma unroll
    for (int rr = 0; rr < 16; ++rr) {
        const int row = 32 * wid + 2 * rr + rhalf;      // filter index
        const int np  = n0 + colr;
        const size_t o = (size_t)(b * NF + row) * LOUT + np;
        f32x4 v = *reinterpret_cast<const f32x4*>(&sm.c[row][colr]);
        if (np + 3 < LOUT && (long)(o + 3) < out_elems) {
            *reinterpret_cast<f32x4u*>(out + o) = v;
        } else {
#pragma unroll
            for (int r = 0; r < 4; ++r)
                if (np + r < LOUT && (long)(o + r) < out_elems)
                    out[o + r] = v[r];
        }
    }
}

// Complex fallback (folded fp32) in case d_out is interleaved complex.
__global__ __launch_bounds__(256) void gabor_conv_cplx(const float* __restrict__ x,
                                                       float* __restrict__ out,
                                                       long out_elems) {
    __shared__ float sx[256 + KT];
    const int tile = blockIdx.x, g = blockIdx.y, b = blockIdx.z;
    const int t0 = tile * 256, tid = threadIdx.x;
    const float* __restrict__ xb = x + (size_t)b * LIN;
    for (int i = tid; i < 256 + KT - 1; i += 256) {
        int idx = t0 + i;
        sx[i] = (idx < LIN) ? xb[idx] : 0.0f;
    }
    __syncthreads();
    const float* fre = g_filt + g * 16;
    const float* fim = g_filt + KT * NF + g * 16;
    float accre[16], accim[16];
    {
        float x0 = sx[tid], xm = sx[tid + 201];
        const float* c0 = fre;
        const float* cm = fre + 201 * NF;
#pragma unroll
        for (int j = 0; j < 16; ++j) accre[j] = __builtin_fmaf(xm, cm[j], x0 * c0[j]);
#pragma unroll
        for (int j = 0; j < 16; ++j) accim[j] = x0 * fim[j];
    }
#pragma unroll 2
    for (int p = 1; p <= 200; ++p) {
        float x1 = sx[tid + p], x2 = sx[tid + 402 - p];
        float xs = x1 + x2, xd = x1 - x2;
        const float* cr = fre + p * NF;
        const float* ci = fim + p * NF;
#pragma unroll
        for (int j = 0; j < 16; ++j) accre[j] = __builtin_fmaf(xs, cr[j], accre[j]);
#pragma unroll
        for (int j = 0; j < 16; ++j) accim[j] = __builtin_fmaf(xd, ci[j], accim[j]);
    }
    const int t = t0 + tid;
    if (t < LOUT) {
#pragma unroll
        for (int j = 0; j < 16; ++j) {
            size_t o = ((size_t)(b * NF + g * 16 + j) * LOUT + t) * 2;
            if ((long)(o + 1) < out_elems) {
                float2 v; v.x = accre[j]; v.y = accim[j];
                *reinterpret_cast<float2*>(out + o) = v;
            }
        }
    }
}

extern "C" void kernel_launch(void* const* d_in, const int* in_sizes, int n_in,
                              void* d_out, int out_size, void* d_ws, size_t ws_size,
                              hipStream_t stream) {
    const float* x  = (const float*)d_in[0];
    const float* cf = (const float*)d_in[1];
    const float* bw = (const float*)d_in[2];
    float* out = (float*)d_out;
    (void)d_ws; (void)ws_size;

    {
        int n = NF * KP;
        gabor_build_filters<<<(n + 255) / 256, 256, 0, stream>>>(cf, bw);
    }

    const long n_complex = (long)NB * NF * LOUT;
    const bool cplx = ((long)out_size >= 2 * n_complex);

    if (cplx) {
        dim3 grid((LOUT + 255) / 256, NF / 16, NB);
        gabor_conv_cplx<<<grid, 256, 0, stream>>>(x, out, (long)out_size);
    } else {
        dim3 grid((LOUT + NT - 1) / NT, NB);   // (122, 16)
        gabor_conv_mfma<<<grid, TT, 0, stream>>>(x, out, (long)out_size);
    }
}